// Round 2
// baseline (567.880 us; speedup 1.0000x reference)
//
#include <hip/hip_runtime.h>
#include <hip/hip_bf16.h>
#include <cstdint>
#include <cstddef>

// ---------------- types / helpers ----------------
typedef __bf16 bf16x8 __attribute__((ext_vector_type(8)));
typedef __bf16 bf16x4 __attribute__((ext_vector_type(4)));
typedef float  floatx4 __attribute__((ext_vector_type(4)));

#define DEV __device__ __forceinline__

DEV __bf16 f2b(float x) { return (__bf16)x; }

// async global->LDS, 16B per lane. LDS dest semantics: wave-uniform base + lane*16.
DEV void async_ld16(const void* g, void* l) {
    __builtin_amdgcn_global_load_lds(
        (const __attribute__((address_space(1))) unsigned int*)g,
        (__attribute__((address_space(3))) unsigned int*)l,
        16, 0, 0);
}

// ---------------- constants ----------------
#define BATCH 4096
#define DDIM  4624          // 68*68
#define DPAD  4800          // GEMM1 K padded to mult of 192 (75*64, 3-buffer pipeline)
#define LDIM  68
#define EDIM  1024
#define N1    2048          // fc11|fc12 fused
#define KB    2048          // stage-B K (h11|h12)
#define N2PAD 4864          // 19*256
#define NPAIR 2346          // 68*69/2 symmetric pairs
#define K2PAD 2496          // NPAIR padded: 39*64 (mult of 192)

// ======================================================================
// fp32 -> bf16 convert with zero padding. dst[rows_total][DPAD].
// ======================================================================
__global__ void cvt_pad(const float* __restrict__ src, int rows_valid, int K,
                        __bf16* __restrict__ dst, int rows_total) {
    const int gpr = DPAD / 4;   // 1200
    const long total = (long)rows_total * gpr;
    for (long g = blockIdx.x * (long)blockDim.x + threadIdx.x; g < total;
         g += gridDim.x * (long)blockDim.x) {
        int row = (int)(g / gpr);
        int c4  = (int)(g - (long)row * gpr) * 4;
        bf16x4 v;
        if (row < rows_valid && c4 < K) {
            floatx4 f = *(const floatx4*)(src + (size_t)row * K + c4);
            v[0] = f2b(f[0]); v[1] = f2b(f[1]); v[2] = f2b(f[2]); v[3] = f2b(f[3]);
        } else {
            v[0] = v[1] = v[2] = v[3] = (__bf16)0.0f;
        }
        *(bf16x4*)(dst + (size_t)row * DPAD + c4) = v;
    }
}

// w2_pad [144][2048] bf16: rows 0..67 = fc21 in cols 0..1023; rows 68..135 = fc22 in
// cols 1024..2047; everything else 0. (matches hbuf layout h11|h12)
__global__ void pad_w2(const float* __restrict__ w21, const float* __restrict__ w22,
                       __bf16* __restrict__ dst) {
    const int total = 144 * 512;
    for (int g = blockIdx.x * blockDim.x + threadIdx.x; g < total;
         g += gridDim.x * blockDim.x) {
        int row = g >> 9;
        int c4  = (g & 511) * 4;
        bf16x4 v;
        v[0] = v[1] = v[2] = v[3] = (__bf16)0.0f;
        if (row < 68 && c4 < 1024) {
            floatx4 f = *(const floatx4*)(w21 + (size_t)row * EDIM + c4);
            v[0] = f2b(f[0]); v[1] = f2b(f[1]); v[2] = f2b(f[2]); v[3] = f2b(f[3]);
        } else if (row >= 68 && row < 136 && c4 >= 1024) {
            floatx4 f = *(const floatx4*)(w22 + (size_t)(row - 68) * EDIM + (c4 - 1024));
            v[0] = f2b(f[0]); v[1] = f2b(f[1]); v[2] = f2b(f[2]); v[3] = f2b(f[3]);
        }
        *(bf16x4*)(dst + (size_t)row * KB + c4) = v;
    }
}

// ======================================================================
// pair table: p -> (i,j), i<=j, p = i*(137-i)/2 + (j-i). Built in LDS.
// ======================================================================
DEV void build_ptab(unsigned short* ptab, int t, int nthr) {
    for (int i = t; i < LDIM; i += nthr) {
        int p0 = i * (137 - i) / 2;
        for (int j = i; j < LDIM; ++j)
            ptab[p0 + (j - i)] = (unsigned short)((i << 8) | j);
    }
}

// ======================================================================
// w6sym: one block per output row o. dst[o][p] = w6[o][i,j] + w6[o][j,i] (i<j),
// w6[o][i,i] (i==j); zero pad for p>=NPAIR and o>=DDIM.
// ======================================================================
__global__ void w6sym_build(const float* __restrict__ w6, __bf16* __restrict__ dst) {
    __shared__ float row[DDIM];
    __shared__ unsigned short ptab[K2PAD];
    const int o = blockIdx.x;
    const int t = threadIdx.x;
    if (o < DDIM) {
        const float* src = w6 + (size_t)o * DDIM;
        for (int idx = t; idx < DDIM / 4; idx += 256)
            *(floatx4*)(row + idx * 4) = *(const floatx4*)(src + idx * 4);
    }
    build_ptab(ptab, t, 256);
    __syncthreads();
    for (int p4 = t; p4 < K2PAD / 4; p4 += 256) {
        bf16x4 v;
#pragma unroll
        for (int u = 0; u < 4; ++u) {
            int p = p4 * 4 + u;
            float val = 0.f;
            if (o < DDIM && p < NPAIR) {
                int ij = ptab[p];
                int i = ij >> 8, j = ij & 255;
                val = (i == j) ? row[i * LDIM + i] : (row[i * LDIM + j] + row[j * LDIM + i]);
            }
            v[u] = f2b(val);
        }
        *(bf16x4*)(dst + (size_t)o * K2PAD + p4 * 4) = v;
    }
}

// ======================================================================
// main MFMA GEMM: C[M,N] = epi(A[M,K] * W[N,K]^T + bias)
// BM=128 x BN=256, BK=64, 8 waves (2M x 4N, each 64x64 via 4x4 frags of 16x16x32).
// m201-style fine-grained schedule: TRIPLE-buffered LDS (144 KiB), prefetch
// distance 2 K-tiles; each K-tile = 2 PHASES, each phase =
//   { 8 ds_read_b128 subtile  ||  3 global_load_lds (next+2 tile staging)
//     -> s_barrier -> lgkmcnt(0)+sched_barrier -> setprio(1) 16xMFMA setprio(0)
//     -> s_barrier }
// counted s_waitcnt vmcnt(6) ONCE per K-tile (end), never 0 in steady state
// (T3+T4; loads stay in flight across barriers). Safety: tile t lives in buf
// t%3, staged during tile t-2; end-of-tile-(t-1) vmcnt(6) retires exactly tile
// t's 6 loads (in-order vmcnt) before the barrier that opens tile t. Staging
// during tile t targets buf (t+2)%3, whose last reader (tile t-1) finished
// before tile t's opening barrier.
// Chunk XOR-swizzle (chunk ^ (row&7)) on the GLOBAL-side address (m104/m108:
// global_load_lds dest must stay linear); frag ds_read_b128s land 2-way
// aliased (free, m136) -> measured 0 bank conflicts.
// EPI 0: relu(acc + (col<1024 ? b0[col] : b1[col-1024])) -> bf16 outb
// EPI 1: sigmoid(acc + b0[col]) -> fp32 outf, only col < DDIM
// ======================================================================
template <int EPI>
__launch_bounds__(512, 1)
__global__ void gemm_bt(const __bf16* __restrict__ A, int lda,
                        const __bf16* __restrict__ W, int ldb, int KT,
                        __bf16* __restrict__ outb, float* __restrict__ outf, int ldc,
                        const float* __restrict__ bias0, const float* __restrict__ bias1) {
    __shared__ __align__(16) __bf16 smA[3 * 128 * 64];   // 48 KB (3 x 16 KB)
    __shared__ __align__(16) __bf16 smB[3 * 256 * 64];   // 96 KB (3 x 32 KB)

    const int t  = threadIdx.x;
    const int l  = t & 63;
    const int w  = t >> 6;
    const int m0 = blockIdx.x * 128;
    const int n0 = blockIdx.y * 256;
    const int wm = (w & 1) * 64;          // 2 M-waves
    const int wn = (w >> 1) * 64;         // 4 N-waves

    // staging: thread t covers local row (t>>3) (+64/... per load), 16B chunk
    // (t&7) in LDS (linear dest t*16 + 8192*load); global chunk pre-swizzled.
    const int lr = t >> 3;                               // 0..63
    const int sw = (t & 7) ^ (lr & 7);                   // swizzled global chunk
    const __bf16* pa0 = A + (size_t)(m0 + lr) * lda + sw * 8;
    const __bf16* pb0 = W + (size_t)(n0 + lr) * ldb + sw * 8;
    char* dA = (char*)smA + t * 16;
    char* dB = (char*)smB + t * 16;

    // frag-read setup: row r -> LDS chunk ((h<<2)|q) ^ (r&7); r&7 == l&7 for
    // all frags (wm/wn mult of 64, mi*16 ≡ 0 mod 8).
    const int q   = l >> 4;                              // 0..3
    const int ra  = wm + (l & 15);
    const int rb  = wn + (l & 15);
    const int c0b = ((0 | q) ^ (l & 7)) * 16;            // h=0 chunk byte off
    const int c1b = ((4 | q) ^ (l & 7)) * 16;            // h=1 chunk byte off

    floatx4 acc[4][4];
#pragma unroll
    for (int mi = 0; mi < 4; ++mi)
#pragma unroll
        for (int ni = 0; ni < 4; ++ni) {
            floatx4 z = {0.f, 0.f, 0.f, 0.f};
            acc[mi][ni] = z;
        }

    auto STG0 = [&](int tile, int ba, int bb) {   // A rows 0-63, 64-127; B rows 0-63
        const __bf16* sa = pa0 + (size_t)tile * 64;
        const __bf16* sb = pb0 + (size_t)tile * 64;
        async_ld16(sa,                      dA + ba);
        async_ld16(sa + (size_t)64 * lda,   dA + ba + 8192);
        async_ld16(sb,                      dB + bb);
    };
    auto STG1 = [&](int tile, int bb) {           // B rows 64-255
        const __bf16* sb = pb0 + (size_t)tile * 64;
        async_ld16(sb + (size_t)64 * ldb,   dB + bb + 8192);
        async_ld16(sb + (size_t)128 * ldb,  dB + bb + 16384);
        async_ld16(sb + (size_t)192 * ldb,  dB + bb + 24576);
    };
    auto LOADFRAGS = [&](const char* baA, const char* baB, int cb,
                         bf16x8* af, bf16x8* bfr) {
#pragma unroll
        for (int mi = 0; mi < 4; ++mi)
            af[mi] = *(const bf16x8*)(baA + (ra + mi * 16) * 128 + cb);
#pragma unroll
        for (int ni = 0; ni < 4; ++ni)
            bfr[ni] = *(const bf16x8*)(baB + (rb + ni * 16) * 128 + cb);
    };
    auto MFMA16 = [&](bf16x8* af, bf16x8* bfr) {
        __builtin_amdgcn_s_setprio(1);
#pragma unroll
        for (int mi = 0; mi < 4; ++mi)
#pragma unroll
            for (int ni = 0; ni < 4; ++ni)
                acc[mi][ni] = __builtin_amdgcn_mfma_f32_16x16x32_bf16(
                    af[mi], bfr[ni], acc[mi][ni], 0, 0, 0);
        __builtin_amdgcn_s_setprio(0);
    };

// one K-tile = 2 phases. SEN: staging enabled (compile-time). EVM: -1 none,
// 6 counted, 0 drain (compile-time).
#define TILE(BA, BB, SEN, ST, SBA, SBB, EVM)                                \
    {                                                                       \
        const char* baA = (const char*)smA + (BA);                          \
        const char* baB = (const char*)smB + (BB);                          \
        bf16x8 af[4], bfr[4];                                               \
        /* phase 0: k-half 0 */                                             \
        LOADFRAGS(baA, baB, c0b, af, bfr);                                  \
        if (SEN) STG0(ST, SBA, SBB);                                        \
        __builtin_amdgcn_s_barrier();                                       \
        asm volatile("s_waitcnt lgkmcnt(0)" ::: "memory");                  \
        __builtin_amdgcn_sched_barrier(0);                                  \
        MFMA16(af, bfr);                                                    \
        __builtin_amdgcn_s_barrier();                                       \
        /* phase 1: k-half 1 */                                             \
        LOADFRAGS(baA, baB, c1b, af, bfr);                                  \
        if (SEN) STG1(ST, SBB);                                             \
        __builtin_amdgcn_s_barrier();                                       \
        asm volatile("s_waitcnt lgkmcnt(0)" ::: "memory");                  \
        __builtin_amdgcn_sched_barrier(0);                                  \
        MFMA16(af, bfr);                                                    \
        if (EVM == 6) asm volatile("s_waitcnt vmcnt(6)" ::: "memory");      \
        else if (EVM == 0) asm volatile("s_waitcnt vmcnt(0)" ::: "memory"); \
        __builtin_amdgcn_s_barrier();                                       \
    }

    // buffer byte offsets
    enum { A1 = 16384, A2O = 32768, B1 = 32768, B2O = 65536 };

    // prologue: tiles 0,1 in flight (12 loads); retire tile 0's (vmcnt 6)
    STG0(0, 0, 0);   STG1(0, 0);
    STG0(1, A1, B1); STG1(1, B1);
    asm volatile("s_waitcnt vmcnt(6)" ::: "memory");
    __builtin_amdgcn_s_barrier();

    const int G = KT / 3;   // KT multiple of 3
    for (int g = 0; g < G - 1; ++g) {
        const int tt = g * 3;
        TILE(0,   0,   1, tt + 2, A2O, B2O, 6);   // tile t   (buf0), stage t+2 -> buf2
        TILE(A1,  B1,  1, tt + 3, 0,   0,   6);   // tile t+1 (buf1), stage t+3 -> buf0
        TILE(A2O, B2O, 1, tt + 4, A1,  B1,  6);   // tile t+2 (buf2), stage t+4 -> buf1
    }
    // last group: stage only KT-1, then drain
    TILE(0,   0,   1, KT - 1, A2O, B2O, 6);
    TILE(A1,  B1,  0, 0, 0, 0, 0);
    TILE(A2O, B2O, 0, 0, 0, 0, -1);
#undef TILE

    // epilogue: C/D layout col = lane&15, row = (lane>>4)*4 + reg  [m89/m91]
    const int colbase = n0 + wn + (l & 15);
    const int rowbase = m0 + wm + (l >> 4) * 4;
#pragma unroll
    for (int ni = 0; ni < 4; ++ni) {
        int col = colbase + ni * 16;
        if (EPI == 1 && col >= DDIM) continue;
        float bias = (EPI == 0)
                         ? ((col < 1024) ? bias0[col] : bias1[col - 1024])
                         : bias0[col];
#pragma unroll
        for (int mi = 0; mi < 4; ++mi) {
            int row = rowbase + mi * 16;
#pragma unroll
            for (int r = 0; r < 4; ++r) {
                float v = acc[mi][ni][r] + bias;
                if (EPI == 0) {
                    v = v > 0.f ? v : 0.f;
                    outb[(size_t)(row + r) * ldc + col] = f2b(v);
                } else {
                    v = 1.f / (1.f + __expf(-v));
                    outf[(size_t)(row + r) * ldc + col] = v;
                }
            }
        }
    }
}

// ======================================================================
// stage B: muvar[4096][136] += h[4096][2048] * w2_pad[144][2048]^T (K-split x4, atomics)
// ======================================================================
__launch_bounds__(64, 4)
__global__ void gemmB(const __bf16* __restrict__ h, const __bf16* __restrict__ w2,
                      float* __restrict__ muvar) {
    const int l    = threadIdx.x;
    const int m0   = blockIdx.x * 16;
    const int k0   = blockIdx.y * 512;
    const int row  = l & 15;
    const int quad = l >> 4;

    floatx4 acc[9];
#pragma unroll
    for (int ni = 0; ni < 9; ++ni) {
        floatx4 z = {0.f, 0.f, 0.f, 0.f};
        acc[ni] = z;
    }

    const __bf16* ap = h + (size_t)(m0 + row) * KB + k0 + quad * 8;
    for (int kt = 0; kt < 16; ++kt) {
        bf16x8 a = *(const bf16x8*)ap;
        ap += 32;
#pragma unroll
        for (int ni = 0; ni < 9; ++ni) {
            const __bf16* bp = w2 + (size_t)(ni * 16 + row) * KB + k0 + kt * 32 + quad * 8;
            bf16x8 b = *(const bf16x8*)bp;
            acc[ni] = __builtin_amdgcn_mfma_f32_16x16x32_bf16(a, b, acc[ni], 0, 0, 0);
        }
    }
#pragma unroll
    for (int ni = 0; ni < 9; ++ni) {
        int col = ni * 16 + row;
        if (col < 136) {
#pragma unroll
            for (int r = 0; r < 4; ++r) {
                int orow = m0 + quad * 4 + r;
                atomicAdd(&muvar[(size_t)orow * 136 + col], acc[ni][r]);
            }
        }
    }
}

// ======================================================================
// decode (fp32): mu/logvar(+bias) -> z -> h3_0 -> h4_0 -> h51 -> symmetric-pair A2
// also writes mu, logvar, y. Branches 1..4 dead (recon uses h51 only).
// ======================================================================
__global__ void decode(const float* __restrict__ muvar, const float* __restrict__ eps,
                       const float* __restrict__ b21, const float* __restrict__ b22,
                       const float* __restrict__ W3, const float* __restrict__ b3,
                       const float* __restrict__ W4, const float* __restrict__ b4,
                       const float* __restrict__ W5, const float* __restrict__ b5,
                       const float* __restrict__ fcyw, const float* __restrict__ fcyb,
                       float* __restrict__ out_mu, float* __restrict__ out_lv,
                       float* __restrict__ out_y, __bf16* __restrict__ A2) {
    __shared__ float w3s[DDIM], w4s[DDIM], w5s[DDIM];
    __shared__ float b3s[LDIM], b4s[LDIM], b5s[LDIM], fys[LDIM];
    __shared__ float zb[16][LDIM], h3b[16][LDIM], h51b[16][LDIM];
    __shared__ unsigned short ptab[K2PAD];

    const int t  = threadIdx.x;
    const int r0 = blockIdx.x * 16;

    for (int i = t; i < DDIM; i += 256) {  // branch 0 = first 68*68 of each tensor
        w3s[i] = W3[i];
        w4s[i] = W4[i];
        w5s[i] = W5[i];
    }
    if (t < LDIM) {
        b3s[t] = b3[t];
        b4s[t] = b4[t];
        b5s[t] = b5[t];
        fys[t] = fcyw[t];
    }
    build_ptab(ptab, t, 256);
    __syncthreads();

    for (int idx = t; idx < 16 * LDIM; idx += 256) {
        int r = idx / LDIM, o = idx - r * LDIM;
        int row = r0 + r;
        float mu = muvar[(size_t)row * 136 + o] + b21[o];
        float lv = muvar[(size_t)row * 136 + 68 + o] + b22[o];
        float z  = mu + eps[(size_t)row * LDIM + o] * __expf(0.5f * lv);
        zb[r][o] = z;
        out_mu[(size_t)row * LDIM + o] = mu;
        out_lv[(size_t)row * LDIM + o] = lv;
    }
    if (t < 16) {
        int row = r0 + t;
        float s = fcyb[0];
        for (int o = 0; o < LDIM; ++o)
            s += (muvar[(size_t)row * 136 + o] + b21[o]) * fys[o];
        out_y[row] = s;
    }
    __syncthreads();

    // h3_0 = z @ W3_0^T + b3_0   (branch 0: NO sigmoid)
    for (int idx = t; idx < 16 * LDIM; idx += 256) {
        int r = idx / LDIM, o = idx - r * LDIM;
        float s = b3s[o];
        for (int d = 0; d < LDIM; ++d) s += zb[r][d] * w3s[o * LDIM + d];
        h3b[r][o] = s;
    }
    __syncthreads();

    // h4_0 = sigmoid(h3_0 @ W4_0^T + b4_0)  -> reuse zb
    for (int idx = t; idx < 16 * LDIM; idx += 256) {
        int r = idx / LDIM, o = idx - r * LDIM;
        float s = b4s[o];
        for (int d = 0; d < LDIM; ++d) s += h3b[r][d] * w4s[o * LDIM + d];
        zb[r][o] = 1.f / (1.f + __expf(-s));
    }
    __syncthreads();

    // h51 = h4_0 @ W5_0^T + b5_0
    for (int idx = t; idx < 16 * LDIM; idx += 256) {
        int r = idx / LDIM, o = idx - r * LDIM;
        float s = b5s[o];
        for (int d = 0; d < LDIM; ++d) s += zb[r][d] * w5s[o * LDIM + d];
        h51b[r][o] = s;
    }
    __syncthreads();

    // symmetric-pair "outer product": A2[row][p] = h51[i]*h51[j] (factor 2 folded into w6sym)
    for (int idx = t; idx < 16 * (K2PAD / 4); idx += 256) {
        int r  = idx / (K2PAD / 4);
        int p4 = (idx - r * (K2PAD / 4)) * 4;
        int row = r0 + r;
        bf16x4 v;
#pragma unroll
        for (int u = 0; u < 4; ++u) {
            int p = p4 + u;
            float val = 0.f;
            if (p < NPAIR) {
                int ij = ptab[p];
                val = h51b[r][ij >> 8] * h51b[r][ij & 255];
            }
            v[u] = f2b(val);
        }
        *(bf16x4*)(A2 + (size_t)row * K2PAD + p4) = v;
    }
}

// ======================================================================
extern "C" void kernel_launch(void* const* d_in, const int* in_sizes, int n_in,
                              void* d_out, int out_size, void* d_ws, size_t ws_size,
                              hipStream_t stream) {
    const float* x    = (const float*)d_in[0];
    const float* eps  = (const float*)d_in[1];
    const float* w11  = (const float*)d_in[2];
    const float* b11  = (const float*)d_in[3];
    const float* w12  = (const float*)d_in[4];
    const float* b12  = (const float*)d_in[5];
    const float* w21  = (const float*)d_in[6];
    const float* b21  = (const float*)d_in[7];
    const float* w22  = (const float*)d_in[8];
    const float* b22  = (const float*)d_in[9];
    const float* W3   = (const float*)d_in[10];
    const float* b3   = (const float*)d_in[11];
    const float* W4   = (const float*)d_in[12];
    const float* b4   = (const float*)d_in[13];
    const float* W5   = (const float*)d_in[14];
    const float* b5   = (const float*)d_in[15];
    const float* w6   = (const float*)d_in[16];
    const float* b6   = (const float*)d_in[17];
    const float* fcyw = (const float*)d_in[18];
    const float* fcyb = (const float*)d_in[19];

    float* out       = (float*)d_out;
    float* out_recon = out;
    float* out_mu    = out + (size_t)BATCH * DDIM;
    float* out_lv    = out_mu + (size_t)BATCH * LDIM;
    float* out_y     = out_lv + (size_t)BATCH * LDIM;

    // ws layout (bytes, 256B-aligned)
    char* ws = (char*)d_ws;
    size_t off = 0;
    __bf16* xb     = (__bf16*)(ws + off); off += (size_t)BATCH * DPAD * 2;   // 39.3 MB
    __bf16* w1_pad = (__bf16*)(ws + off); off += (size_t)N1 * DPAD * 2;      // 19.7 MB
    __bf16* w6s    = (__bf16*)(ws + off); off += (size_t)N2PAD * K2PAD * 2;  // 24.3 MB
    __bf16* hbuf   = (__bf16*)(ws + off); off += (size_t)BATCH * KB * 2;     // 16.8 MB
    __bf16* w2_pad = (__bf16*)(ws + off); off += (size_t)144 * KB * 2;       //  0.6 MB
    float*  muvar  = (float*) (ws + off); off += (size_t)BATCH * 136 * 4;    //  2.2 MB
    __bf16* A2     = (__bf16*)(ws + off);                                    // 20.4 MB
    // total ~123 MB

    hipMemsetAsync(muvar, 0, (size_t)BATCH * 136 * 4, stream);

    // fp32 -> zero-padded bf16 staging buffers
    cvt_pad<<<2048, 256, 0, stream>>>(x, BATCH, DDIM, xb, BATCH);
    cvt_pad<<<512, 256, 0, stream>>>(w11, 1024, DDIM, w1_pad, 1024);
    cvt_pad<<<512, 256, 0, stream>>>(w12, 1024, DDIM, w1_pad + (size_t)1024 * DPAD, 1024);
    w6sym_build<<<N2PAD, 256, 0, stream>>>(w6, w6s);
    pad_w2<<<72, 256, 0, stream>>>(w21, w22, w2_pad);

    // GEMM1: h = relu(x @ [fc11|fc12]^T + b)   M=4096 N=2048 K=4800 (KT=75)
    gemm_bt<0><<<dim3(BATCH / 128, N1 / 256), 512, 0, stream>>>(
        xb, DPAD, w1_pad, DPAD, DPAD / 64, hbuf, nullptr, N1, b11, b12);

    // stage B: muvar = h @ w2_pad^T (K-split, atomics)
    gemmB<<<dim3(BATCH / 16, 4), 64, 0, stream>>>(hbuf, w2_pad, muvar);

    // decode + symmetric-pair A2 (bf16, zero-padded)
    decode<<<BATCH / 16, 256, 0, stream>>>(muvar, eps, b21, b22, W3, b3, W4, b4, W5, b5,
                                           fcyw, fcyb, out_mu, out_lv, out_y, A2);

    // GEMM2: recon = sigmoid(A2sym @ w6sym^T + b6)  M=4096 N=4864(valid 4624) K=2496 (KT=39)
    gemm_bt<1><<<dim3(BATCH / 128, N2PAD / 256), 512, 0, stream>>>(
        A2, K2PAD, w6s, K2PAD, K2PAD / 64, nullptr, out_recon, DDIM, b6, nullptr);
}

// Round 3
// 537.879 us; speedup vs baseline: 1.0558x; 1.0558x over previous
//
#include <hip/hip_runtime.h>
#include <hip/hip_bf16.h>
#include <cstdint>
#include <cstddef>

// ---------------- types / helpers ----------------
typedef __bf16 bf16x8 __attribute__((ext_vector_type(8)));
typedef __bf16 bf16x4 __attribute__((ext_vector_type(4)));
typedef float  floatx4 __attribute__((ext_vector_type(4)));

#define DEV __device__ __forceinline__

DEV __bf16 f2b(float x) { return (__bf16)x; }

// async global->LDS, 16B per lane. LDS dest semantics: wave-uniform base + lane*16.
DEV void async_ld16(const void* g, void* l) {
    __builtin_amdgcn_global_load_lds(
        (const __attribute__((address_space(1))) unsigned int*)g,
        (__attribute__((address_space(3))) unsigned int*)l,
        16, 0, 0);
}

// ---------------- constants ----------------
#define BATCH 4096
#define DDIM  4624          // 68*68
#define DPAD  4672          // GEMM1 K padded to mult of 64 (73*64)
#define LDIM  68
#define EDIM  1024
#define N1    2048          // fc11|fc12 fused
#define KB    2048          // stage-B K (h11|h12)
#define N2PAD 4736          // 37*128
#define NPAIR 2346          // 68*69/2 symmetric pairs
#define K2PAD 2368          // NPAIR padded: 37*64
#define NBX   32            // M-tiles (4096/128) for both GEMMs

// ======================================================================
// pair table: p -> (i,j), i<=j, p = i*(137-i)/2 + (j-i). Built in LDS.
// ======================================================================
DEV void build_ptab(unsigned short* ptab, int t, int nthr) {
    for (int i = t; i < LDIM; i += nthr) {
        int p0 = i * (137 - i) / 2;
        for (int j = i; j < LDIM; ++j)
            ptab[p0 + (j - i)] = (unsigned short)((i << 8) | j);
    }
}

// ======================================================================
// merged prep kernel (single launch; blockIdx ranges select role):
//   [0,2048)     cvt x      -> xb     [4096][DPAD] bf16, zero col-pad
//   [2048,2560)  cvt w11    -> w1_pad rows 0..1023
//   [2560,3072)  cvt w12    -> w1_pad rows 1024..2047
//   [3072,3144)  pad_w2     -> w2_pad [144][2048]
//   [3144,7880)  w6sym      -> w6s    [N2PAD][K2PAD]
// ======================================================================
#define PREP_GRID 7880
__global__ __launch_bounds__(256) void prep(
        const float* __restrict__ x, const float* __restrict__ w11,
        const float* __restrict__ w12, const float* __restrict__ w21,
        const float* __restrict__ w22, const float* __restrict__ w6,
        __bf16* __restrict__ xb, __bf16* __restrict__ w1_pad,
        __bf16* __restrict__ w2_pad, __bf16* __restrict__ w6s) {
    __shared__ float rowbuf[DDIM];
    __shared__ unsigned short ptab[K2PAD];
    const int b = blockIdx.x;
    const int t = threadIdx.x;

    if (b < 3072) {
        // ---- cvt_pad role (fp32 [rows][DDIM] -> bf16 [rows][DPAD], zero pad)
        const float* src;
        __bf16* dst;
        int rows, lb, vg;
        if (b < 2048)      { src = x;   dst = xb;                          rows = BATCH; lb = b;        vg = 2048; }
        else if (b < 2560) { src = w11; dst = w1_pad;                      rows = 1024;  lb = b - 2048; vg = 512; }
        else               { src = w12; dst = w1_pad + (size_t)1024 * DPAD; rows = 1024; lb = b - 2560; vg = 512; }
        const int gpr = DPAD / 4;   // 1168
        const long total = (long)rows * gpr;
        for (long g = lb * 256L + t; g < total; g += vg * 256L) {
            int row = (int)(g / gpr);
            int c4  = (int)(g - (long)row * gpr) * 4;
            bf16x4 v;
            if (c4 < DDIM) {
                floatx4 f = *(const floatx4*)(src + (size_t)row * DDIM + c4);
                v[0] = f2b(f[0]); v[1] = f2b(f[1]); v[2] = f2b(f[2]); v[3] = f2b(f[3]);
            } else {
                v[0] = v[1] = v[2] = v[3] = (__bf16)0.0f;
            }
            *(bf16x4*)(dst + (size_t)row * DPAD + c4) = v;
        }
    } else if (b < 3144) {
        // ---- pad_w2 role: [144][2048], rows 0..67 = fc21 cols 0..1023,
        //      rows 68..135 = fc22 cols 1024..2047, else 0
        const int lb = b - 3072;
        const int total = 144 * 512;
        for (int g = lb * 256 + t; g < total; g += 72 * 256) {
            int row = g >> 9;
            int c4  = (g & 511) * 4;
            bf16x4 v;
            v[0] = v[1] = v[2] = v[3] = (__bf16)0.0f;
            if (row < 68 && c4 < 1024) {
                floatx4 f = *(const floatx4*)(w21 + (size_t)row * EDIM + c4);
                v[0] = f2b(f[0]); v[1] = f2b(f[1]); v[2] = f2b(f[2]); v[3] = f2b(f[3]);
            } else if (row >= 68 && row < 136 && c4 >= 1024) {
                floatx4 f = *(const floatx4*)(w22 + (size_t)(row - 68) * EDIM + (c4 - 1024));
                v[0] = f2b(f[0]); v[1] = f2b(f[1]); v[2] = f2b(f[2]); v[3] = f2b(f[3]);
            }
            *(bf16x4*)(w2_pad + (size_t)row * KB + c4) = v;
        }
    } else {
        // ---- w6sym role: one block per output row o.
        // dst[o][p] = w6[o][i,j]+w6[o][j,i] (i<j), w6[o][i,i] (i==j); zero pad.
        const int o = b - 3144;             // 0..N2PAD-1
        if (o < DDIM) {
            const float* src = w6 + (size_t)o * DDIM;
            for (int idx = t; idx < DDIM / 4; idx += 256)
                *(floatx4*)(rowbuf + idx * 4) = *(const floatx4*)(src + idx * 4);
        }
        build_ptab(ptab, t, 256);
        __syncthreads();
        for (int p4 = t; p4 < K2PAD / 4; p4 += 256) {
            bf16x4 v;
#pragma unroll
            for (int u = 0; u < 4; ++u) {
                int p = p4 * 4 + u;
                float val = 0.f;
                if (o < DDIM && p < NPAIR) {
                    int ij = ptab[p];
                    int i = ij >> 8, j = ij & 255;
                    val = (i == j) ? rowbuf[i * LDIM + i]
                                   : (rowbuf[i * LDIM + j] + rowbuf[j * LDIM + i]);
                }
                v[u] = f2b(val);
            }
            *(bf16x4*)(w6s + (size_t)o * K2PAD + p4 * 4) = v;
        }
    }
}

// ======================================================================
// main MFMA GEMM: C[M,N] = epi(A[M,K] * W[N,K]^T + bias)
// ROUND-0 PROVEN STRUCTURE (36.4% MfmaUtil, m97-ceiling): 128x128 tile, BK=64,
// 4 waves each 64x64 via 4x4 frags of 16x16x32, 2 k-halves per staging,
// 2-block/CU TLP hides the barrier drain (m114). LDS chunk XOR-swizzle
// (chunk ^ (row&7)) on the GLOBAL-side address (m104/m108) -> 0 bank conflicts.
// NEW vs round 0: 1-D grid + bijective XCD swizzle (T1, m157/m192): grid
// divisible by 8, each XCD gets a contiguous chunk of M-fastest tile ids ->
// B/W panel reuse in per-XCD L2 (FETCH_SIZE was 2.7x ideal).
// EPI 0: relu(acc + (col<1024 ? b0[col] : b1[col-1024])) -> bf16 outb
// EPI 1: sigmoid(acc + b0[col]) -> fp32 outf, only col < DDIM
// ======================================================================
template <int EPI>
__launch_bounds__(256, 2)
__global__ void gemm_bt(const __bf16* __restrict__ A, int lda,
                        const __bf16* __restrict__ W, int ldb, int KT,
                        __bf16* __restrict__ outb, float* __restrict__ outf, int ldc,
                        const float* __restrict__ bias0, const float* __restrict__ bias1) {
    __shared__ __align__(16) __bf16 smA[128 * 64];   // 16 KB
    __shared__ __align__(16) __bf16 smB[128 * 64];   // 16 KB

    const int t  = threadIdx.x;
    const int l  = t & 63;
    const int w  = t >> 6;
    // XCD-aware remap: HW assigns blockIdx round-robin to 8 XCDs; give XCD x
    // the contiguous work chunk [x*cpx, (x+1)*cpx). Requires gridDim.x % 8 == 0.
    const int cpx = gridDim.x >> 3;
    const int swz = (blockIdx.x & 7) * cpx + (blockIdx.x >> 3);
    const int m0  = (swz & (NBX - 1)) * 128;
    const int n0  = (swz / NBX) * 128;
    const int wm = (w & 1) * 64;
    const int wn = (w >> 1) * 64;

    // staging: thread t covers row t/8 (+32 per instr i=0..3), 16B chunk (t%8)
    // in LDS; fetches swizzled global chunk (t%8)^((t/8)&7). (i*32 ≡ 0 mod 8,
    // so the swizzle term is constant across i.)
    const int srow   = t >> 3;                       // 0..31
    const int schunk = (t & 7) ^ (srow & 7);
    const __bf16* pa = A + (size_t)(m0 + srow) * lda + schunk * 8;
    const __bf16* pb = W + (size_t)(n0 + srow) * ldb + schunk * 8;
    char* dA = (char*)smA + t * 16;
    char* dB = (char*)smB + t * 16;

    floatx4 acc[4][4];
#pragma unroll
    for (int mi = 0; mi < 4; ++mi)
#pragma unroll
        for (int ni = 0; ni < 4; ++ni) {
            floatx4 z = {0.f, 0.f, 0.f, 0.f};
            acc[mi][ni] = z;
        }

    for (int kt = 0; kt < KT; ++kt) {
#pragma unroll
        for (int i = 0; i < 4; ++i) {
            async_ld16(pa + (size_t)i * 32 * lda, dA + i * 4096);
            async_ld16(pb + (size_t)i * 32 * ldb, dB + i * 4096);
        }
        pa += 64; pb += 64;
        __syncthreads();

#pragma unroll
        for (int h = 0; h < 2; ++h) {
            bf16x8 af[4], bfr[4];
#pragma unroll
            for (int mi = 0; mi < 4; ++mi) {
                int r = wm + mi * 16 + (l & 15);
                int c = ((h << 2) | (l >> 4)) ^ (r & 7);
                af[mi] = *(const bf16x8*)((const char*)smA + r * 128 + c * 16);
            }
#pragma unroll
            for (int ni = 0; ni < 4; ++ni) {
                int r = wn + ni * 16 + (l & 15);
                int c = ((h << 2) | (l >> 4)) ^ (r & 7);
                bfr[ni] = *(const bf16x8*)((const char*)smB + r * 128 + c * 16);
            }
#pragma unroll
            for (int mi = 0; mi < 4; ++mi)
#pragma unroll
                for (int ni = 0; ni < 4; ++ni)
                    acc[mi][ni] = __builtin_amdgcn_mfma_f32_16x16x32_bf16(af[mi], bfr[ni],
                                                                         acc[mi][ni], 0, 0, 0);
        }
        __syncthreads();
    }

    // epilogue: C/D layout col = lane&15, row = (lane>>4)*4 + reg  [m89/m91]
    const int colbase = n0 + wn + (l & 15);
    const int rowbase = m0 + wm + (l >> 4) * 4;
#pragma unroll
    for (int ni = 0; ni < 4; ++ni) {
        int col = colbase + ni * 16;
        if (EPI == 1 && col >= DDIM) continue;
        float bias = (EPI == 0)
                         ? ((col < 1024) ? bias0[col] : bias1[col - 1024])
                         : bias0[col];
#pragma unroll
        for (int mi = 0; mi < 4; ++mi) {
            int row = rowbase + mi * 16;
#pragma unroll
            for (int r = 0; r < 4; ++r) {
                float v = acc[mi][ni][r] + bias;
                if (EPI == 0) {
                    v = v > 0.f ? v : 0.f;
                    outb[(size_t)(row + r) * ldc + col] = f2b(v);
                } else {
                    v = 1.f / (1.f + __expf(-v));
                    outf[(size_t)(row + r) * ldc + col] = v;
                }
            }
        }
    }
}

// ======================================================================
// stage B: muvar[slice][4096][136] = h[4096][2048] * w2_pad[144][2048]^T,
// K split x4 over blockIdx.y into PER-SLICE buffers (plain stores, no atomics,
// no memset; decode sums the 4 slices).
// ======================================================================
__launch_bounds__(64, 4)
__global__ void gemmB(const __bf16* __restrict__ h, const __bf16* __restrict__ w2,
                      float* __restrict__ muvar) {
    const int l    = threadIdx.x;
    const int m0   = blockIdx.x * 16;
    const int k0   = blockIdx.y * 512;
    const int row  = l & 15;
    const int quad = l >> 4;
    float* mv = muvar + (size_t)blockIdx.y * BATCH * 136;

    floatx4 acc[9];
#pragma unroll
    for (int ni = 0; ni < 9; ++ni) {
        floatx4 z = {0.f, 0.f, 0.f, 0.f};
        acc[ni] = z;
    }

    const __bf16* ap = h + (size_t)(m0 + row) * KB + k0 + quad * 8;
    for (int kt = 0; kt < 16; ++kt) {
        bf16x8 a = *(const bf16x8*)ap;
        ap += 32;
#pragma unroll
        for (int ni = 0; ni < 9; ++ni) {
            const __bf16* bp = w2 + (size_t)(ni * 16 + row) * KB + k0 + kt * 32 + quad * 8;
            bf16x8 b = *(const bf16x8*)bp;
            acc[ni] = __builtin_amdgcn_mfma_f32_16x16x32_bf16(a, b, acc[ni], 0, 0, 0);
        }
    }
#pragma unroll
    for (int ni = 0; ni < 9; ++ni) {
        int col = ni * 16 + row;
        if (col < 136) {
#pragma unroll
            for (int r = 0; r < 4; ++r) {
                int orow = m0 + quad * 4 + r;
                mv[(size_t)orow * 136 + col] = acc[ni][r];
            }
        }
    }
}

// ======================================================================
// decode (fp32): mu/logvar (sum of 4 K-slices + bias) -> z -> h3_0 -> h4_0 ->
// h51 -> symmetric-pair A2. Also writes mu, logvar, y. Branches 1..4 dead.
// ======================================================================
__global__ void decode(const float* __restrict__ muvar, const float* __restrict__ eps,
                       const float* __restrict__ b21, const float* __restrict__ b22,
                       const float* __restrict__ W3, const float* __restrict__ b3,
                       const float* __restrict__ W4, const float* __restrict__ b4,
                       const float* __restrict__ W5, const float* __restrict__ b5,
                       const float* __restrict__ fcyw, const float* __restrict__ fcyb,
                       float* __restrict__ out_mu, float* __restrict__ out_lv,
                       float* __restrict__ out_y, __bf16* __restrict__ A2) {
    __shared__ float w3s[DDIM], w4s[DDIM], w5s[DDIM];
    __shared__ float b3s[LDIM], b4s[LDIM], b5s[LDIM], fys[LDIM];
    __shared__ float zb[16][LDIM], h3b[16][LDIM], h51b[16][LDIM], mub[16][LDIM];
    __shared__ unsigned short ptab[K2PAD];

    const int t  = threadIdx.x;
    const int r0 = blockIdx.x * 16;

    for (int i = t; i < DDIM; i += 256) {  // branch 0 = first 68*68 of each tensor
        w3s[i] = W3[i];
        w4s[i] = W4[i];
        w5s[i] = W5[i];
    }
    if (t < LDIM) {
        b3s[t] = b3[t];
        b4s[t] = b4[t];
        b5s[t] = b5[t];
        fys[t] = fcyw[t];
    }
    build_ptab(ptab, t, 256);
    __syncthreads();

    for (int idx = t; idx < 16 * LDIM; idx += 256) {
        int r = idx / LDIM, o = idx - r * LDIM;
        int row = r0 + r;
        float mu = b21[o];
        float lv = b22[o];
#pragma unroll
        for (int s = 0; s < 4; ++s) {
            const float* mv = muvar + (size_t)s * BATCH * 136 + (size_t)row * 136;
            mu += mv[o];
            lv += mv[68 + o];
        }
        float z = mu + eps[(size_t)row * LDIM + o] * __expf(0.5f * lv);
        zb[r][o]  = z;
        mub[r][o] = mu;
        out_mu[(size_t)row * LDIM + o] = mu;
        out_lv[(size_t)row * LDIM + o] = lv;
    }
    __syncthreads();

    if (t < 16) {
        int row = r0 + t;
        float s = fcyb[0];
        for (int o = 0; o < LDIM; ++o)
            s += mub[t][o] * fys[o];
        out_y[row] = s;
    }

    // h3_0 = z @ W3_0^T + b3_0   (branch 0: NO sigmoid)
    for (int idx = t; idx < 16 * LDIM; idx += 256) {
        int r = idx / LDIM, o = idx - r * LDIM;
        float s = b3s[o];
        for (int d = 0; d < LDIM; ++d) s += zb[r][d] * w3s[o * LDIM + d];
        h3b[r][o] = s;
    }
    __syncthreads();

    // h4_0 = sigmoid(h3_0 @ W4_0^T + b4_0)  -> reuse zb
    for (int idx = t; idx < 16 * LDIM; idx += 256) {
        int r = idx / LDIM, o = idx - r * LDIM;
        float s = b4s[o];
        for (int d = 0; d < LDIM; ++d) s += h3b[r][d] * w4s[o * LDIM + d];
        zb[r][o] = 1.f / (1.f + __expf(-s));
    }
    __syncthreads();

    // h51 = h4_0 @ W5_0^T + b5_0
    for (int idx = t; idx < 16 * LDIM; idx += 256) {
        int r = idx / LDIM, o = idx - r * LDIM;
        float s = b5s[o];
        for (int d = 0; d < LDIM; ++d) s += zb[r][d] * w5s[o * LDIM + d];
        h51b[r][o] = s;
    }
    __syncthreads();

    // symmetric-pair "outer product": A2[row][p] = h51[i]*h51[j] (factor 2 folded into w6sym)
    for (int idx = t; idx < 16 * (K2PAD / 4); idx += 256) {
        int r  = idx / (K2PAD / 4);
        int p4 = (idx - r * (K2PAD / 4)) * 4;
        int row = r0 + r;
        bf16x4 v;
#pragma unroll
        for (int u = 0; u < 4; ++u) {
            int p = p4 + u;
            float val = 0.f;
            if (p < NPAIR) {
                int ij = ptab[p];
                val = h51b[r][ij >> 8] * h51b[r][ij & 255];
            }
            v[u] = f2b(val);
        }
        *(bf16x4*)(A2 + (size_t)row * K2PAD + p4) = v;
    }
}

// ======================================================================
extern "C" void kernel_launch(void* const* d_in, const int* in_sizes, int n_in,
                              void* d_out, int out_size, void* d_ws, size_t ws_size,
                              hipStream_t stream) {
    const float* x    = (const float*)d_in[0];
    const float* eps  = (const float*)d_in[1];
    const float* w11  = (const float*)d_in[2];
    const float* b11  = (const float*)d_in[3];
    const float* w12  = (const float*)d_in[4];
    const float* b12  = (const float*)d_in[5];
    const float* w21  = (const float*)d_in[6];
    const float* b21  = (const float*)d_in[7];
    const float* w22  = (const float*)d_in[8];
    const float* b22  = (const float*)d_in[9];
    const float* W3   = (const float*)d_in[10];
    const float* b3   = (const float*)d_in[11];
    const float* W4   = (const float*)d_in[12];
    const float* b4   = (const float*)d_in[13];
    const float* W5   = (const float*)d_in[14];
    const float* b5   = (const float*)d_in[15];
    const float* w6   = (const float*)d_in[16];
    const float* b6   = (const float*)d_in[17];
    const float* fcyw = (const float*)d_in[18];
    const float* fcyb = (const float*)d_in[19];

    float* out       = (float*)d_out;
    float* out_recon = out;
    float* out_mu    = out + (size_t)BATCH * DDIM;
    float* out_lv    = out_mu + (size_t)BATCH * LDIM;
    float* out_y     = out_lv + (size_t)BATCH * LDIM;

    // ws layout (bytes, 256B-aligned)
    char* ws = (char*)d_ws;
    size_t off = 0;
    __bf16* xb     = (__bf16*)(ws + off); off += (size_t)BATCH * DPAD * 2;    // 38.3 MB
    __bf16* w1_pad = (__bf16*)(ws + off); off += (size_t)N1 * DPAD * 2;       // 19.1 MB
    __bf16* w6s    = (__bf16*)(ws + off); off += (size_t)N2PAD * K2PAD * 2;   // 22.4 MB
    __bf16* hbuf   = (__bf16*)(ws + off); off += (size_t)BATCH * KB * 2;      // 16.8 MB
    __bf16* w2_pad = (__bf16*)(ws + off); off += (size_t)144 * KB * 2;        //  0.6 MB
    float*  muvar  = (float*) (ws + off); off += (size_t)4 * BATCH * 136 * 4; //  8.9 MB
    __bf16* A2     = (__bf16*)(ws + off);                                     // 19.4 MB
    // total ~126 MB

    // single merged prep launch (cvt x / w11 / w12, pad_w2, w6sym)
    prep<<<PREP_GRID, 256, 0, stream>>>(x, w11, w12, w21, w22, w6,
                                        xb, w1_pad, w2_pad, w6s);

    // GEMM1: h = relu(x @ [fc11|fc12]^T + b)   M=4096 N=2048 K=4672, grid 512 (div 8)
    gemm_bt<0><<<(BATCH / 128) * (N1 / 128), 256, 0, stream>>>(
        xb, DPAD, w1_pad, DPAD, DPAD / 64, hbuf, nullptr, N1, b11, b12);

    // stage B: muvar slices = h @ w2_pad^T (per-slice stores, no atomics)
    gemmB<<<dim3(BATCH / 16, 4), 64, 0, stream>>>(hbuf, w2_pad, muvar);

    // decode + symmetric-pair A2 (bf16, zero-padded)
    decode<<<BATCH / 16, 256, 0, stream>>>(muvar, eps, b21, b22, W3, b3, W4, b4, W5, b5,
                                           fcyw, fcyb, out_mu, out_lv, out_y, A2);

    // GEMM2: recon = sigmoid(A2sym @ w6sym^T + b6)  M=4096 N=4736(valid 4624) K=2368,
    // grid 1184 (div 8)
    gemm_bt<1><<<(BATCH / 128) * (N2PAD / 128), 256, 0, stream>>>(
        A2, K2PAD, w6s, K2PAD, K2PAD / 64, nullptr, out_recon, DDIM, b6, nullptr);
}

// Round 4
// 524.115 us; speedup vs baseline: 1.0835x; 1.0263x over previous
//
#include <hip/hip_runtime.h>
#include <hip/hip_bf16.h>
#include <cstdint>
#include <cstddef>

// ---------------- types / helpers ----------------
typedef __bf16 bf16x8 __attribute__((ext_vector_type(8)));
typedef __bf16 bf16x4 __attribute__((ext_vector_type(4)));
typedef float  floatx4 __attribute__((ext_vector_type(4)));

#define DEV __device__ __forceinline__

DEV __bf16 f2b(float x) { return (__bf16)x; }

// async global->LDS, 16B per lane. LDS dest semantics: wave-uniform base + lane*16.
DEV void async_ld16(const void* g, void* l) {
    __builtin_amdgcn_global_load_lds(
        (const __attribute__((address_space(1))) unsigned int*)g,
        (__attribute__((address_space(3))) unsigned int*)l,
        16, 0, 0);
}

// ---------------- constants ----------------
#define BATCH 4096
#define DDIM  4624          // 68*68
#define DPAD  4672          // GEMM1 K padded to mult of 64 (73*64)
#define LDIM  68
#define EDIM  1024
#define N1    2048          // fc11|fc12 fused
#define KB    2048          // stage-B K (h11|h12)
#define N2PAD 4736          // 37*128
#define NPAIR 2346          // 68*69/2 symmetric pairs
#define K2PAD 2368          // NPAIR padded: 37*64

// ======================================================================
// pair table: p -> (i,j), i<=j, p = i*(137-i)/2 + (j-i). Built in LDS.
// ======================================================================
DEV void build_ptab(unsigned short* ptab, int t, int nthr) {
    for (int i = t; i < LDIM; i += nthr) {
        int p0 = i * (137 - i) / 2;
        for (int j = i; j < LDIM; ++j)
            ptab[p0 + (j - i)] = (unsigned short)((i << 8) | j);
    }
}

// ======================================================================
// merged prep kernel (single launch; blockIdx ranges select role):
//   [0,2048)     cvt x      -> xb     [4096][DPAD] bf16, zero col-pad
//   [2048,2560)  cvt w11    -> w1_pad rows 0..1023
//   [2560,3072)  cvt w12    -> w1_pad rows 1024..2047
//   [3072,3144)  pad_w2     -> w2_pad [144][2048]
//   [3144,7880)  w6sym      -> w6s    [N2PAD][K2PAD]
// ======================================================================
#define PREP_GRID 7880
__global__ __launch_bounds__(256) void prep(
        const float* __restrict__ x, const float* __restrict__ w11,
        const float* __restrict__ w12, const float* __restrict__ w21,
        const float* __restrict__ w22, const float* __restrict__ w6,
        __bf16* __restrict__ xb, __bf16* __restrict__ w1_pad,
        __bf16* __restrict__ w2_pad, __bf16* __restrict__ w6s) {
    __shared__ float rowbuf[DDIM];
    __shared__ unsigned short ptab[K2PAD];
    const int b = blockIdx.x;
    const int t = threadIdx.x;

    if (b < 3072) {
        // ---- cvt_pad role (fp32 [rows][DDIM] -> bf16 [rows][DPAD], zero pad)
        const float* src;
        __bf16* dst;
        int rows, lb, vg;
        if (b < 2048)      { src = x;   dst = xb;                          rows = BATCH; lb = b;        vg = 2048; }
        else if (b < 2560) { src = w11; dst = w1_pad;                      rows = 1024;  lb = b - 2048; vg = 512; }
        else               { src = w12; dst = w1_pad + (size_t)1024 * DPAD; rows = 1024; lb = b - 2560; vg = 512; }
        const int gpr = DPAD / 4;   // 1168
        const long total = (long)rows * gpr;
        for (long g = lb * 256L + t; g < total; g += vg * 256L) {
            int row = (int)(g / gpr);
            int c4  = (int)(g - (long)row * gpr) * 4;
            bf16x4 v;
            if (c4 < DDIM) {
                floatx4 f = *(const floatx4*)(src + (size_t)row * DDIM + c4);
                v[0] = f2b(f[0]); v[1] = f2b(f[1]); v[2] = f2b(f[2]); v[3] = f2b(f[3]);
            } else {
                v[0] = v[1] = v[2] = v[3] = (__bf16)0.0f;
            }
            *(bf16x4*)(dst + (size_t)row * DPAD + c4) = v;
        }
    } else if (b < 3144) {
        // ---- pad_w2 role: [144][2048], rows 0..67 = fc21 cols 0..1023,
        //      rows 68..135 = fc22 cols 1024..2047, else 0
        const int lb = b - 3072;
        const int total = 144 * 512;
        for (int g = lb * 256 + t; g < total; g += 72 * 256) {
            int row = g >> 9;
            int c4  = (g & 511) * 4;
            bf16x4 v;
            v[0] = v[1] = v[2] = v[3] = (__bf16)0.0f;
            if (row < 68 && c4 < 1024) {
                floatx4 f = *(const floatx4*)(w21 + (size_t)row * EDIM + c4);
                v[0] = f2b(f[0]); v[1] = f2b(f[1]); v[2] = f2b(f[2]); v[3] = f2b(f[3]);
            } else if (row >= 68 && row < 136 && c4 >= 1024) {
                floatx4 f = *(const floatx4*)(w22 + (size_t)(row - 68) * EDIM + (c4 - 1024));
                v[0] = f2b(f[0]); v[1] = f2b(f[1]); v[2] = f2b(f[2]); v[3] = f2b(f[3]);
            }
            *(bf16x4*)(w2_pad + (size_t)row * KB + c4) = v;
        }
    } else {
        // ---- w6sym role: one block per output row o.
        // dst[o][p] = w6[o][i,j]+w6[o][j,i] (i<j), w6[o][i,i] (i==j); zero pad.
        const int o = b - 3144;             // 0..N2PAD-1
        if (o < DDIM) {
            const float* src = w6 + (size_t)o * DDIM;
            for (int idx = t; idx < DDIM / 4; idx += 256)
                *(floatx4*)(rowbuf + idx * 4) = *(const floatx4*)(src + idx * 4);
        }
        build_ptab(ptab, t, 256);
        __syncthreads();
        for (int p4 = t; p4 < K2PAD / 4; p4 += 256) {
            bf16x4 v;
#pragma unroll
            for (int u = 0; u < 4; ++u) {
                int p = p4 * 4 + u;
                float val = 0.f;
                if (o < DDIM && p < NPAIR) {
                    int ij = ptab[p];
                    int i = ij >> 8, j = ij & 255;
                    val = (i == j) ? rowbuf[i * LDIM + i]
                                   : (rowbuf[i * LDIM + j] + rowbuf[j * LDIM + i]);
                }
                v[u] = f2b(val);
            }
            *(bf16x4*)(w6s + (size_t)o * K2PAD + p4 * 4) = v;
        }
    }
}

// ======================================================================
// main MFMA GEMM: C[M,N] = epi(A[M,K] * W[N,K]^T + bias)
// ROUND-0 PROVEN STRUCTURE (36.4% MfmaUtil, m97-ceiling): 128x128 tile, BK=64,
// 4 waves each 64x64 via 4x4 frags of 16x16x32, 2 k-halves per staging,
// 2-block/CU TLP hides the barrier drain (m114). Natural 2-D grid (x = M-tile
// fastest) — measured best L2 locality (FETCH 112 MB vs 228 MB with chunked
// XCD swizzle; working set is L3-fit so swizzle hurts, m160 + round-3 A/B).
// LDS chunk XOR-swizzle (chunk ^ (row&7)) on the GLOBAL-side address
// (m104/m108) -> frag ds_read_b128s 2-way aliased (free, m136), 0 conflicts.
// EPI 0: relu(acc + (col<1024 ? b0[col] : b1[col-1024])) -> bf16 outb
// EPI 1: sigmoid(acc + b0[col]) -> fp32 outf, only col < DDIM
// ======================================================================
template <int EPI>
__launch_bounds__(256, 2)
__global__ void gemm_bt(const __bf16* __restrict__ A, int lda,
                        const __bf16* __restrict__ W, int ldb, int KT,
                        __bf16* __restrict__ outb, float* __restrict__ outf, int ldc,
                        const float* __restrict__ bias0, const float* __restrict__ bias1) {
    __shared__ __align__(16) __bf16 smA[128 * 64];   // 16 KB
    __shared__ __align__(16) __bf16 smB[128 * 64];   // 16 KB

    const int t  = threadIdx.x;
    const int l  = t & 63;
    const int w  = t >> 6;
    const int m0 = blockIdx.x * 128;
    const int n0 = blockIdx.y * 128;
    const int wm = (w & 1) * 64;
    const int wn = (w >> 1) * 64;

    // staging: thread t covers row t/8 (+32 per instr i=0..3), 16B chunk (t%8)
    // in LDS; fetches swizzled global chunk (t%8)^((t/8)&7). (i*32 ≡ 0 mod 8,
    // so the swizzle term is constant across i.)
    const int srow   = t >> 3;                       // 0..31
    const int schunk = (t & 7) ^ (srow & 7);
    const __bf16* pa = A + (size_t)(m0 + srow) * lda + schunk * 8;
    const __bf16* pb = W + (size_t)(n0 + srow) * ldb + schunk * 8;
    char* dA = (char*)smA + t * 16;
    char* dB = (char*)smB + t * 16;

    floatx4 acc[4][4];
#pragma unroll
    for (int mi = 0; mi < 4; ++mi)
#pragma unroll
        for (int ni = 0; ni < 4; ++ni) {
            floatx4 z = {0.f, 0.f, 0.f, 0.f};
            acc[mi][ni] = z;
        }

    for (int kt = 0; kt < KT; ++kt) {
#pragma unroll
        for (int i = 0; i < 4; ++i) {
            async_ld16(pa + (size_t)i * 32 * lda, dA + i * 4096);
            async_ld16(pb + (size_t)i * 32 * ldb, dB + i * 4096);
        }
        pa += 64; pb += 64;
        __syncthreads();

#pragma unroll
        for (int h = 0; h < 2; ++h) {
            bf16x8 af[4], bfr[4];
#pragma unroll
            for (int mi = 0; mi < 4; ++mi) {
                int r = wm + mi * 16 + (l & 15);
                int c = ((h << 2) | (l >> 4)) ^ (r & 7);
                af[mi] = *(const bf16x8*)((const char*)smA + r * 128 + c * 16);
            }
#pragma unroll
            for (int ni = 0; ni < 4; ++ni) {
                int r = wn + ni * 16 + (l & 15);
                int c = ((h << 2) | (l >> 4)) ^ (r & 7);
                bfr[ni] = *(const bf16x8*)((const char*)smB + r * 128 + c * 16);
            }
#pragma unroll
            for (int mi = 0; mi < 4; ++mi)
#pragma unroll
                for (int ni = 0; ni < 4; ++ni)
                    acc[mi][ni] = __builtin_amdgcn_mfma_f32_16x16x32_bf16(af[mi], bfr[ni],
                                                                         acc[mi][ni], 0, 0, 0);
        }
        __syncthreads();
    }

    // epilogue: C/D layout col = lane&15, row = (lane>>4)*4 + reg  [m89/m91]
    const int colbase = n0 + wn + (l & 15);
    const int rowbase = m0 + wm + (l >> 4) * 4;
#pragma unroll
    for (int ni = 0; ni < 4; ++ni) {
        int col = colbase + ni * 16;
        if (EPI == 1 && col >= DDIM) continue;
        float bias = (EPI == 0)
                         ? ((col < 1024) ? bias0[col] : bias1[col - 1024])
                         : bias0[col];
#pragma unroll
        for (int mi = 0; mi < 4; ++mi) {
            int row = rowbase + mi * 16;
#pragma unroll
            for (int r = 0; r < 4; ++r) {
                float v = acc[mi][ni][r] + bias;
                if (EPI == 0) {
                    v = v > 0.f ? v : 0.f;
                    outb[(size_t)(row + r) * ldc + col] = f2b(v);
                } else {
                    v = 1.f / (1.f + __expf(-v));
                    outf[(size_t)(row + r) * ldc + col] = v;
                }
            }
        }
    }
}

// ======================================================================
// stage B: muvar[slice][4096][136] = h[4096][2048] * w2_pad[144][2048]^T,
// K split x4 over blockIdx.y into PER-SLICE buffers (plain stores, no atomics,
// no memset; decode sums the 4 slices).
// ======================================================================
__launch_bounds__(64, 4)
__global__ void gemmB(const __bf16* __restrict__ h, const __bf16* __restrict__ w2,
                      float* __restrict__ muvar) {
    const int l    = threadIdx.x;
    const int m0   = blockIdx.x * 16;
    const int k0   = blockIdx.y * 512;
    const int row  = l & 15;
    const int quad = l >> 4;
    float* mv = muvar + (size_t)blockIdx.y * BATCH * 136;

    floatx4 acc[9];
#pragma unroll
    for (int ni = 0; ni < 9; ++ni) {
        floatx4 z = {0.f, 0.f, 0.f, 0.f};
        acc[ni] = z;
    }

    const __bf16* ap = h + (size_t)(m0 + row) * KB + k0 + quad * 8;
    for (int kt = 0; kt < 16; ++kt) {
        bf16x8 a = *(const bf16x8*)ap;
        ap += 32;
#pragma unroll
        for (int ni = 0; ni < 9; ++ni) {
            const __bf16* bp = w2 + (size_t)(ni * 16 + row) * KB + k0 + kt * 32 + quad * 8;
            bf16x8 b = *(const bf16x8*)bp;
            acc[ni] = __builtin_amdgcn_mfma_f32_16x16x32_bf16(a, b, acc[ni], 0, 0, 0);
        }
    }
#pragma unroll
    for (int ni = 0; ni < 9; ++ni) {
        int col = ni * 16 + row;
        if (col < 136) {
#pragma unroll
            for (int r = 0; r < 4; ++r) {
                int orow = m0 + quad * 4 + r;
                mv[(size_t)orow * 136 + col] = acc[ni][r];
            }
        }
    }
}

// ======================================================================
// decode (fp32): mu/logvar (sum of 4 K-slices + bias) -> z -> h3_0 -> h4_0 ->
// h51 -> symmetric-pair A2. Also writes mu, logvar, y. Branches 1..4 dead.
// ======================================================================
__global__ void decode(const float* __restrict__ muvar, const float* __restrict__ eps,
                       const float* __restrict__ b21, const float* __restrict__ b22,
                       const float* __restrict__ W3, const float* __restrict__ b3,
                       const float* __restrict__ W4, const float* __restrict__ b4,
                       const float* __restrict__ W5, const float* __restrict__ b5,
                       const float* __restrict__ fcyw, const float* __restrict__ fcyb,
                       float* __restrict__ out_mu, float* __restrict__ out_lv,
                       float* __restrict__ out_y, __bf16* __restrict__ A2) {
    __shared__ float w3s[DDIM], w4s[DDIM], w5s[DDIM];
    __shared__ float b3s[LDIM], b4s[LDIM], b5s[LDIM], fys[LDIM];
    __shared__ float zb[16][LDIM], h3b[16][LDIM], h51b[16][LDIM], mub[16][LDIM];
    __shared__ unsigned short ptab[K2PAD];

    const int t  = threadIdx.x;
    const int r0 = blockIdx.x * 16;

    for (int i = t; i < DDIM; i += 256) {  // branch 0 = first 68*68 of each tensor
        w3s[i] = W3[i];
        w4s[i] = W4[i];
        w5s[i] = W5[i];
    }
    if (t < LDIM) {
        b3s[t] = b3[t];
        b4s[t] = b4[t];
        b5s[t] = b5[t];
        fys[t] = fcyw[t];
    }
    build_ptab(ptab, t, 256);
    __syncthreads();

    for (int idx = t; idx < 16 * LDIM; idx += 256) {
        int r = idx / LDIM, o = idx - r * LDIM;
        int row = r0 + r;
        float mu = b21[o];
        float lv = b22[o];
#pragma unroll
        for (int s = 0; s < 4; ++s) {
            const float* mv = muvar + (size_t)s * BATCH * 136 + (size_t)row * 136;
            mu += mv[o];
            lv += mv[68 + o];
        }
        float z = mu + eps[(size_t)row * LDIM + o] * __expf(0.5f * lv);
        zb[r][o]  = z;
        mub[r][o] = mu;
        out_mu[(size_t)row * LDIM + o] = mu;
        out_lv[(size_t)row * LDIM + o] = lv;
    }
    __syncthreads();

    if (t < 16) {
        int row = r0 + t;
        float s = fcyb[0];
        for (int o = 0; o < LDIM; ++o)
            s += mub[t][o] * fys[o];
        out_y[row] = s;
    }

    // h3_0 = z @ W3_0^T + b3_0   (branch 0: NO sigmoid)
    for (int idx = t; idx < 16 * LDIM; idx += 256) {
        int r = idx / LDIM, o = idx - r * LDIM;
        float s = b3s[o];
        for (int d = 0; d < LDIM; ++d) s += zb[r][d] * w3s[o * LDIM + d];
        h3b[r][o] = s;
    }
    __syncthreads();

    // h4_0 = sigmoid(h3_0 @ W4_0^T + b4_0)  -> reuse zb
    for (int idx = t; idx < 16 * LDIM; idx += 256) {
        int r = idx / LDIM, o = idx - r * LDIM;
        float s = b4s[o];
        for (int d = 0; d < LDIM; ++d) s += h3b[r][d] * w4s[o * LDIM + d];
        zb[r][o] = 1.f / (1.f + __expf(-s));
    }
    __syncthreads();

    // h51 = h4_0 @ W5_0^T + b5_0
    for (int idx = t; idx < 16 * LDIM; idx += 256) {
        int r = idx / LDIM, o = idx - r * LDIM;
        float s = b5s[o];
        for (int d = 0; d < LDIM; ++d) s += zb[r][d] * w5s[o * LDIM + d];
        h51b[r][o] = s;
    }
    __syncthreads();

    // symmetric-pair "outer product": A2[row][p] = h51[i]*h51[j] (factor 2 folded into w6sym)
    for (int idx = t; idx < 16 * (K2PAD / 4); idx += 256) {
        int r  = idx / (K2PAD / 4);
        int p4 = (idx - r * (K2PAD / 4)) * 4;
        int row = r0 + r;
        bf16x4 v;
#pragma unroll
        for (int u = 0; u < 4; ++u) {
            int p = p4 + u;
            float val = 0.f;
            if (p < NPAIR) {
                int ij = ptab[p];
                val = h51b[r][ij >> 8] * h51b[r][ij & 255];
            }
            v[u] = f2b(val);
        }
        *(bf16x4*)(A2 + (size_t)row * K2PAD + p4) = v;
    }
}

// ======================================================================
extern "C" void kernel_launch(void* const* d_in, const int* in_sizes, int n_in,
                              void* d_out, int out_size, void* d_ws, size_t ws_size,
                              hipStream_t stream) {
    const float* x    = (const float*)d_in[0];
    const float* eps  = (const float*)d_in[1];
    const float* w11  = (const float*)d_in[2];
    const float* b11  = (const float*)d_in[3];
    const float* w12  = (const float*)d_in[4];
    const float* b12  = (const float*)d_in[5];
    const float* w21  = (const float*)d_in[6];
    const float* b21  = (const float*)d_in[7];
    const float* w22  = (const float*)d_in[8];
    const float* b22  = (const float*)d_in[9];
    const float* W3   = (const float*)d_in[10];
    const float* b3   = (const float*)d_in[11];
    const float* W4   = (const float*)d_in[12];
    const float* b4   = (const float*)d_in[13];
    const float* W5   = (const float*)d_in[14];
    const float* b5   = (const float*)d_in[15];
    const float* w6   = (const float*)d_in[16];
    const float* b6   = (const float*)d_in[17];
    const float* fcyw = (const float*)d_in[18];
    const float* fcyb = (const float*)d_in[19];

    float* out       = (float*)d_out;
    float* out_recon = out;
    float* out_mu    = out + (size_t)BATCH * DDIM;
    float* out_lv    = out_mu + (size_t)BATCH * LDIM;
    float* out_y     = out_lv + (size_t)BATCH * LDIM;

    // ws layout (bytes, 256B-aligned)
    char* ws = (char*)d_ws;
    size_t off = 0;
    __bf16* xb     = (__bf16*)(ws + off); off += (size_t)BATCH * DPAD * 2;    // 38.3 MB
    __bf16* w1_pad = (__bf16*)(ws + off); off += (size_t)N1 * DPAD * 2;       // 19.1 MB
    __bf16* w6s    = (__bf16*)(ws + off); off += (size_t)N2PAD * K2PAD * 2;   // 22.4 MB
    __bf16* hbuf   = (__bf16*)(ws + off); off += (size_t)BATCH * KB * 2;      // 16.8 MB
    __bf16* w2_pad = (__bf16*)(ws + off); off += (size_t)144 * KB * 2;        //  0.6 MB
    float*  muvar  = (float*) (ws + off); off += (size_t)4 * BATCH * 136 * 4; //  8.9 MB
    __bf16* A2     = (__bf16*)(ws + off);                                     // 19.4 MB
    // total ~126 MB

    // single merged prep launch (cvt x / w11 / w12, pad_w2, w6sym)
    prep<<<PREP_GRID, 256, 0, stream>>>(x, w11, w12, w21, w22, w6,
                                        xb, w1_pad, w2_pad, w6s);

    // GEMM1: h = relu(x @ [fc11|fc12]^T + b)   M=4096 N=2048 K=4672
    gemm_bt<0><<<dim3(32, 16), 256, 0, stream>>>(
        xb, DPAD, w1_pad, DPAD, DPAD / 64, hbuf, nullptr, N1, b11, b12);

    // stage B: muvar slices = h @ w2_pad^T (per-slice stores, no atomics)
    gemmB<<<dim3(BATCH / 16, 4), 64, 0, stream>>>(hbuf, w2_pad, muvar);

    // decode + symmetric-pair A2 (bf16, zero-padded)
    decode<<<BATCH / 16, 256, 0, stream>>>(muvar, eps, b21, b22, W3, b3, W4, b4, W5, b5,
                                           fcyw, fcyb, out_mu, out_lv, out_y, A2);

    // GEMM2: recon = sigmoid(A2sym @ w6sym^T + b6)  M=4096 N=4736(valid 4624) K=2368
    gemm_bt<1><<<dim3(32, N2PAD / 128), 256, 0, stream>>>(
        A2, K2PAD, w6s, K2PAD, K2PAD / 64, nullptr, out_recon, DDIM, b6, nullptr);
}

// Round 5
// 517.483 us; speedup vs baseline: 1.0974x; 1.0128x over previous
//
#include <hip/hip_runtime.h>
#include <hip/hip_bf16.h>
#include <cstdint>
#include <cstddef>

// ---------------- types / helpers ----------------
typedef __bf16 bf16x8 __attribute__((ext_vector_type(8)));
typedef __bf16 bf16x4 __attribute__((ext_vector_type(4)));
typedef float  floatx4 __attribute__((ext_vector_type(4)));

#define DEV __device__ __forceinline__

DEV __bf16 f2b(float x) { return (__bf16)x; }

// async global->LDS, 16B per lane. LDS dest semantics: wave-uniform base + lane*16.
DEV void async_ld16(const void* g, void* l) {
    __builtin_amdgcn_global_load_lds(
        (const __attribute__((address_space(1))) unsigned int*)g,
        (__attribute__((address_space(3))) unsigned int*)l,
        16, 0, 0);
}

// ---------------- constants ----------------
#define BATCH 4096
#define DDIM  4624          // 68*68
#define DPAD  4672          // GEMM1 K padded to mult of 64 (73*64)
#define LDIM  68
#define LPAD  69            // LDS stride for 68-wide weight rows (kills 8-way bank conflict)
#define EDIM  1024
#define N1    2048          // fc11|fc12 fused
#define KB    2048          // stage-B K (h11|h12)
#define N2PAD 4736          // 37*128
#define NPAIR 2346          // 68*69/2 symmetric pairs
#define K2PAD 2368          // NPAIR padded: 37*64

// ======================================================================
// pair table: p -> (i,j), i<=j, p = i*(137-i)/2 + (j-i). Built in LDS.
// ======================================================================
DEV void build_ptab(unsigned short* ptab, int t, int nthr) {
    for (int i = t; i < LDIM; i += nthr) {
        int p0 = i * (137 - i) / 2;
        for (int j = i; j < LDIM; ++j)
            ptab[p0 + (j - i)] = (unsigned short)((i << 8) | j);
    }
}

// ======================================================================
// merged prep kernel (single launch; blockIdx ranges select role), 8-wide:
//   [0,2048)     cvt x      -> xb     [4096][DPAD] bf16, zero col-pad
//   [2048,2560)  cvt w11    -> w1_pad rows 0..1023
//   [2560,3072)  cvt w12    -> w1_pad rows 1024..2047
//   [3072,3144)  pad_w2     -> w2_pad [144][2048]
//   [3144,7880)  w6sym      -> w6s    [N2PAD][K2PAD]
// ======================================================================
#define PREP_GRID 7880
__global__ __launch_bounds__(256) void prep(
        const float* __restrict__ x, const float* __restrict__ w11,
        const float* __restrict__ w12, const float* __restrict__ w21,
        const float* __restrict__ w22, const float* __restrict__ w6,
        __bf16* __restrict__ xb, __bf16* __restrict__ w1_pad,
        __bf16* __restrict__ w2_pad, __bf16* __restrict__ w6s) {
    __shared__ float rowbuf[DDIM];
    __shared__ unsigned short ptab[K2PAD];
    const int b = blockIdx.x;
    const int t = threadIdx.x;

    if (b < 3072) {
        // ---- cvt_pad role (fp32 [rows][DDIM] -> bf16 [rows][DPAD], zero pad)
        // 8 elems / thread-iter. DDIM and DPAD are multiples of 8.
        const float* src;
        __bf16* dst;
        int rows, lb, vg;
        if (b < 2048)      { src = x;   dst = xb;                           rows = BATCH; lb = b;        vg = 2048; }
        else if (b < 2560) { src = w11; dst = w1_pad;                       rows = 1024;  lb = b - 2048; vg = 512; }
        else               { src = w12; dst = w1_pad + (size_t)1024 * DPAD; rows = 1024;  lb = b - 2560; vg = 512; }
        const int gpr = DPAD / 8;   // 584
        const long total = (long)rows * gpr;
        for (long g = lb * 256L + t; g < total; g += vg * 256L) {
            int row = (int)(g / gpr);
            int c8  = (int)(g - (long)row * gpr) * 8;
            bf16x8 v;
            if (c8 < DDIM) {
                const float* p = src + (size_t)row * DDIM + c8;
                floatx4 f0 = *(const floatx4*)p;
                floatx4 f1 = *(const floatx4*)(p + 4);
                v[0] = f2b(f0[0]); v[1] = f2b(f0[1]); v[2] = f2b(f0[2]); v[3] = f2b(f0[3]);
                v[4] = f2b(f1[0]); v[5] = f2b(f1[1]); v[6] = f2b(f1[2]); v[7] = f2b(f1[3]);
            } else {
#pragma unroll
                for (int u = 0; u < 8; ++u) v[u] = (__bf16)0.0f;
            }
            *(bf16x8*)(dst + (size_t)row * DPAD + c8) = v;
        }
    } else if (b < 3144) {
        // ---- pad_w2 role: [144][2048], rows 0..67 = fc21 cols 0..1023,
        //      rows 68..135 = fc22 cols 1024..2047, else 0
        const int lb = b - 3072;
        const int total = 144 * 256;     // 8-wide units
        for (int g = lb * 256 + t; g < total; g += 72 * 256) {
            int row = g >> 8;
            int c8  = (g & 255) * 8;
            bf16x8 v;
#pragma unroll
            for (int u = 0; u < 8; ++u) v[u] = (__bf16)0.0f;
            if (row < 68 && c8 < 1024) {
                const float* p = w21 + (size_t)row * EDIM + c8;
                floatx4 f0 = *(const floatx4*)p;
                floatx4 f1 = *(const floatx4*)(p + 4);
                v[0] = f2b(f0[0]); v[1] = f2b(f0[1]); v[2] = f2b(f0[2]); v[3] = f2b(f0[3]);
                v[4] = f2b(f1[0]); v[5] = f2b(f1[1]); v[6] = f2b(f1[2]); v[7] = f2b(f1[3]);
            } else if (row >= 68 && row < 136 && c8 >= 1024) {
                const float* p = w22 + (size_t)(row - 68) * EDIM + (c8 - 1024);
                floatx4 f0 = *(const floatx4*)p;
                floatx4 f1 = *(const floatx4*)(p + 4);
                v[0] = f2b(f0[0]); v[1] = f2b(f0[1]); v[2] = f2b(f0[2]); v[3] = f2b(f0[3]);
                v[4] = f2b(f1[0]); v[5] = f2b(f1[1]); v[6] = f2b(f1[2]); v[7] = f2b(f1[3]);
            }
            *(bf16x8*)(w2_pad + (size_t)row * KB + c8) = v;
        }
    } else {
        // ---- w6sym role: one block per output row o.
        // dst[o][p] = w6[o][i,j]+w6[o][j,i] (i<j), w6[o][i,i] (i==j); zero pad.
        const int o = b - 3144;             // 0..N2PAD-1
        if (o < DDIM) {
            const float* src = w6 + (size_t)o * DDIM;
            for (int idx = t; idx < DDIM / 4; idx += 256)
                *(floatx4*)(rowbuf + idx * 4) = *(const floatx4*)(src + idx * 4);
        }
        build_ptab(ptab, t, 256);
        __syncthreads();
        for (int p8 = t; p8 < K2PAD / 8; p8 += 256) {
            bf16x8 v;
#pragma unroll
            for (int u = 0; u < 8; ++u) {
                int p = p8 * 8 + u;
                float val = 0.f;
                if (o < DDIM && p < NPAIR) {
                    int ij = ptab[p];
                    int i = ij >> 8, j = ij & 255;
                    val = (i == j) ? rowbuf[i * LDIM + i]
                                   : (rowbuf[i * LDIM + j] + rowbuf[j * LDIM + i]);
                }
                v[u] = f2b(val);
            }
            *(bf16x8*)(w6s + (size_t)o * K2PAD + p8 * 8) = v;
        }
    }
}

// ======================================================================
// main MFMA GEMM: C[M,N] = epi(A[M,K] * W[N,K]^T + bias)
// ROUND-0 PROVEN STRUCTURE — FROZEN (3 structure experiments falsified:
// r1 coarse-pipeline −21%, r2 fine-phase −26%, r3 chunked XCD swz −12%).
// 128x128 tile, BK=64, 4 waves each 64x64 via 4x4 frags of 16x16x32,
// 2-block/CU TLP hides the barrier drain (m114). Natural 2-D grid = best L2
// locality (FETCH 112 vs 228 MB chunked; working set L3-fit, m160).
// LDS chunk XOR-swizzle on the GLOBAL-side address (m104/m108) -> 0 conflicts.
// EPI 0: relu(acc + (col<1024 ? b0[col] : b1[col-1024])) -> bf16 outb
// EPI 1: sigmoid(acc + b0[col]) -> fp32 outf, only col < DDIM
// ======================================================================
template <int EPI>
__launch_bounds__(256, 2)
__global__ void gemm_bt(const __bf16* __restrict__ A, int lda,
                        const __bf16* __restrict__ W, int ldb, int KT,
                        __bf16* __restrict__ outb, float* __restrict__ outf, int ldc,
                        const float* __restrict__ bias0, const float* __restrict__ bias1) {
    __shared__ __align__(16) __bf16 smA[128 * 64];   // 16 KB
    __shared__ __align__(16) __bf16 smB[128 * 64];   // 16 KB

    const int t  = threadIdx.x;
    const int l  = t & 63;
    const int w  = t >> 6;
    const int m0 = blockIdx.x * 128;
    const int n0 = blockIdx.y * 128;
    const int wm = (w & 1) * 64;
    const int wn = (w >> 1) * 64;

    // staging: thread t covers row t/8 (+32 per instr i=0..3), 16B chunk (t%8)
    // in LDS; fetches swizzled global chunk (t%8)^((t/8)&7). (i*32 ≡ 0 mod 8,
    // so the swizzle term is constant across i.)
    const int srow   = t >> 3;                       // 0..31
    const int schunk = (t & 7) ^ (srow & 7);
    const __bf16* pa = A + (size_t)(m0 + srow) * lda + schunk * 8;
    const __bf16* pb = W + (size_t)(n0 + srow) * ldb + schunk * 8;
    char* dA = (char*)smA + t * 16;
    char* dB = (char*)smB + t * 16;

    floatx4 acc[4][4];
#pragma unroll
    for (int mi = 0; mi < 4; ++mi)
#pragma unroll
        for (int ni = 0; ni < 4; ++ni) {
            floatx4 z = {0.f, 0.f, 0.f, 0.f};
            acc[mi][ni] = z;
        }

    for (int kt = 0; kt < KT; ++kt) {
#pragma unroll
        for (int i = 0; i < 4; ++i) {
            async_ld16(pa + (size_t)i * 32 * lda, dA + i * 4096);
            async_ld16(pb + (size_t)i * 32 * ldb, dB + i * 4096);
        }
        pa += 64; pb += 64;
        __syncthreads();

#pragma unroll
        for (int h = 0; h < 2; ++h) {
            bf16x8 af[4], bfr[4];
#pragma unroll
            for (int mi = 0; mi < 4; ++mi) {
                int r = wm + mi * 16 + (l & 15);
                int c = ((h << 2) | (l >> 4)) ^ (r & 7);
                af[mi] = *(const bf16x8*)((const char*)smA + r * 128 + c * 16);
            }
#pragma unroll
            for (int ni = 0; ni < 4; ++ni) {
                int r = wn + ni * 16 + (l & 15);
                int c = ((h << 2) | (l >> 4)) ^ (r & 7);
                bfr[ni] = *(const bf16x8*)((const char*)smB + r * 128 + c * 16);
            }
#pragma unroll
            for (int mi = 0; mi < 4; ++mi)
#pragma unroll
                for (int ni = 0; ni < 4; ++ni)
                    acc[mi][ni] = __builtin_amdgcn_mfma_f32_16x16x32_bf16(af[mi], bfr[ni],
                                                                         acc[mi][ni], 0, 0, 0);
        }
        __syncthreads();
    }

    // epilogue: C/D layout col = lane&15, row = (lane>>4)*4 + reg  [m89/m91]
    const int colbase = n0 + wn + (l & 15);
    const int rowbase = m0 + wm + (l >> 4) * 4;
#pragma unroll
    for (int ni = 0; ni < 4; ++ni) {
        int col = colbase + ni * 16;
        if (EPI == 1 && col >= DDIM) continue;
        float bias = (EPI == 0)
                         ? ((col < 1024) ? bias0[col] : bias1[col - 1024])
                         : bias0[col];
#pragma unroll
        for (int mi = 0; mi < 4; ++mi) {
            int row = rowbase + mi * 16;
#pragma unroll
            for (int r = 0; r < 4; ++r) {
                float v = acc[mi][ni][r] + bias;
                if (EPI == 0) {
                    v = v > 0.f ? v : 0.f;
                    outb[(size_t)(row + r) * ldc + col] = f2b(v);
                } else {
                    v = 1.f / (1.f + __expf(-v));
                    outf[(size_t)(row + r) * ldc + col] = v;
                }
            }
        }
    }
}

// ======================================================================
// decode_f (fused gemmB + decode): one block per 16 batch rows.
// Wave w computes K-slice [w*512,(w+1)*512) of muvar[16][136] = h @ w2^T via
// MFMA (exactly the old gemmB body), partials -> LDS; then fp32 decode chain:
// mu/lv (4-slice sum + bias) -> z -> h3_0 -> h4_0 -> h51 -> symmetric-pair A2.
// Weight LDS rows padded to stride 69 (conflict-free matvec reads).
// ======================================================================
__global__ __launch_bounds__(256) void decode_f(
        const __bf16* __restrict__ h, const __bf16* __restrict__ w2,
        const float* __restrict__ eps,
        const float* __restrict__ b21, const float* __restrict__ b22,
        const float* __restrict__ W3, const float* __restrict__ b3,
        const float* __restrict__ W4, const float* __restrict__ b4,
        const float* __restrict__ W5, const float* __restrict__ b5,
        const float* __restrict__ fcyw, const float* __restrict__ fcyb,
        float* __restrict__ out_mu, float* __restrict__ out_lv,
        float* __restrict__ out_y, __bf16* __restrict__ A2) {
    __shared__ float muv[4][16][136];                    // 34.8 KB partials
    __shared__ float w3s[LDIM * LPAD], w4s[LDIM * LPAD], w5s[LDIM * LPAD];  // 56.3 KB
    __shared__ float b3s[LDIM], b4s[LDIM], b5s[LDIM], fys[LDIM];
    __shared__ float zb[16][LDIM], h3b[16][LDIM], h51b[16][LDIM], mub[16][LDIM];
    __shared__ unsigned short ptab[K2PAD];
    // total ~114 KB LDS

    const int t  = threadIdx.x;
    const int l  = t & 63;
    const int w  = t >> 6;
    const int r0 = blockIdx.x * 16;

    // ---- stage-B MFMA part (old gemmB body; k0 = w*512) ----
    {
        const int row  = l & 15;
        const int quad = l >> 4;
        const int k0   = w * 512;
        floatx4 acc[9];
#pragma unroll
        for (int ni = 0; ni < 9; ++ni) {
            floatx4 z = {0.f, 0.f, 0.f, 0.f};
            acc[ni] = z;
        }
        const __bf16* ap = h + (size_t)(r0 + row) * KB + k0 + quad * 8;
        for (int kt = 0; kt < 16; ++kt) {
            bf16x8 a = *(const bf16x8*)ap;
            ap += 32;
#pragma unroll
            for (int ni = 0; ni < 9; ++ni) {
                const __bf16* bp = w2 + (size_t)(ni * 16 + row) * KB + k0 + kt * 32 + quad * 8;
                bf16x8 b = *(const bf16x8*)bp;
                acc[ni] = __builtin_amdgcn_mfma_f32_16x16x32_bf16(a, b, acc[ni], 0, 0, 0);
            }
        }
#pragma unroll
        for (int ni = 0; ni < 9; ++ni) {
            int col = ni * 16 + row;
            if (col < 136) {
#pragma unroll
                for (int r = 0; r < 4; ++r)
                    muv[w][quad * 4 + r][col] = acc[ni][r];
            }
        }
    }

    // ---- load decode weights into LDS (stride-69 padded) ----
    for (int i = t; i < DDIM; i += 256) {
        int o = i / LDIM, d = i - o * LDIM;
        int dst = o * LPAD + d;
        w3s[dst] = W3[i];
        w4s[dst] = W4[i];
        w5s[dst] = W5[i];
    }
    if (t < LDIM) {
        b3s[t] = b3[t];
        b4s[t] = b4[t];
        b5s[t] = b5[t];
        fys[t] = fcyw[t];
    }
    build_ptab(ptab, t, 256);
    __syncthreads();

    // ---- mu / logvar / z ----
    for (int idx = t; idx < 16 * LDIM; idx += 256) {
        int r = idx / LDIM, o = idx - r * LDIM;
        int row = r0 + r;
        float mu = b21[o] + muv[0][r][o] + muv[1][r][o] + muv[2][r][o] + muv[3][r][o];
        float lv = b22[o] + muv[0][r][68 + o] + muv[1][r][68 + o]
                          + muv[2][r][68 + o] + muv[3][r][68 + o];
        float z = mu + eps[(size_t)row * LDIM + o] * __expf(0.5f * lv);
        zb[r][o]  = z;
        mub[r][o] = mu;
        out_mu[(size_t)row * LDIM + o] = mu;
        out_lv[(size_t)row * LDIM + o] = lv;
    }
    __syncthreads();

    if (t < 16) {
        int row = r0 + t;
        float s = fcyb[0];
        for (int o = 0; o < LDIM; ++o)
            s += mub[t][o] * fys[o];
        out_y[row] = s;
    }

    // h3_0 = z @ W3_0^T + b3_0   (branch 0: NO sigmoid)
    for (int idx = t; idx < 16 * LDIM; idx += 256) {
        int r = idx / LDIM, o = idx - r * LDIM;
        float s = b3s[o];
        for (int d = 0; d < LDIM; ++d) s += zb[r][d] * w3s[o * LPAD + d];
        h3b[r][o] = s;
    }
    __syncthreads();

    // h4_0 = sigmoid(h3_0 @ W4_0^T + b4_0)  -> reuse zb
    for (int idx = t; idx < 16 * LDIM; idx += 256) {
        int r = idx / LDIM, o = idx - r * LDIM;
        float s = b4s[o];
        for (int d = 0; d < LDIM; ++d) s += h3b[r][d] * w4s[o * LPAD + d];
        zb[r][o] = 1.f / (1.f + __expf(-s));
    }
    __syncthreads();

    // h51 = h4_0 @ W5_0^T + b5_0
    for (int idx = t; idx < 16 * LDIM; idx += 256) {
        int r = idx / LDIM, o = idx - r * LDIM;
        float s = b5s[o];
        for (int d = 0; d < LDIM; ++d) s += zb[r][d] * w5s[o * LPAD + d];
        h51b[r][o] = s;
    }
    __syncthreads();

    // symmetric-pair "outer product": A2[row][p] = h51[i]*h51[j] (factor 2 folded into w6sym)
    for (int idx = t; idx < 16 * (K2PAD / 4); idx += 256) {
        int r  = idx / (K2PAD / 4);
        int p4 = (idx - r * (K2PAD / 4)) * 4;
        int row = r0 + r;
        bf16x4 v;
#pragma unroll
        for (int u = 0; u < 4; ++u) {
            int p = p4 + u;
            float val = 0.f;
            if (p < NPAIR) {
                int ij = ptab[p];
                val = h51b[r][ij >> 8] * h51b[r][ij & 255];
            }
            v[u] = f2b(val);
        }
        *(bf16x4*)(A2 + (size_t)row * K2PAD + p4) = v;
    }
}

// ======================================================================
extern "C" void kernel_launch(void* const* d_in, const int* in_sizes, int n_in,
                              void* d_out, int out_size, void* d_ws, size_t ws_size,
                              hipStream_t stream) {
    const float* x    = (const float*)d_in[0];
    const float* eps  = (const float*)d_in[1];
    const float* w11  = (const float*)d_in[2];
    const float* b11  = (const float*)d_in[3];
    const float* w12  = (const float*)d_in[4];
    const float* b12  = (const float*)d_in[5];
    const float* w21  = (const float*)d_in[6];
    const float* b21  = (const float*)d_in[7];
    const float* w22  = (const float*)d_in[8];
    const float* b22  = (const float*)d_in[9];
    const float* W3   = (const float*)d_in[10];
    const float* b3   = (const float*)d_in[11];
    const float* W4   = (const float*)d_in[12];
    const float* b4   = (const float*)d_in[13];
    const float* W5   = (const float*)d_in[14];
    const float* b5   = (const float*)d_in[15];
    const float* w6   = (const float*)d_in[16];
    const float* b6   = (const float*)d_in[17];
    const float* fcyw = (const float*)d_in[18];
    const float* fcyb = (const float*)d_in[19];

    float* out       = (float*)d_out;
    float* out_recon = out;
    float* out_mu    = out + (size_t)BATCH * DDIM;
    float* out_lv    = out_mu + (size_t)BATCH * LDIM;
    float* out_y     = out_lv + (size_t)BATCH * LDIM;

    // ws layout (bytes, 256B-aligned)
    char* ws = (char*)d_ws;
    size_t off = 0;
    __bf16* xb     = (__bf16*)(ws + off); off += (size_t)BATCH * DPAD * 2;    // 38.3 MB
    __bf16* w1_pad = (__bf16*)(ws + off); off += (size_t)N1 * DPAD * 2;       // 19.1 MB
    __bf16* w6s    = (__bf16*)(ws + off); off += (size_t)N2PAD * K2PAD * 2;   // 22.4 MB
    __bf16* hbuf   = (__bf16*)(ws + off); off += (size_t)BATCH * KB * 2;      // 16.8 MB
    __bf16* w2_pad = (__bf16*)(ws + off); off += (size_t)144 * KB * 2;        //  0.6 MB
    __bf16* A2     = (__bf16*)(ws + off);                                     // 19.4 MB
    // total ~117 MB

    // single merged prep launch (cvt x / w11 / w12, pad_w2, w6sym)
    prep<<<PREP_GRID, 256, 0, stream>>>(x, w11, w12, w21, w22, w6,
                                        xb, w1_pad, w2_pad, w6s);

    // GEMM1: h = relu(x @ [fc11|fc12]^T + b)   M=4096 N=2048 K=4672
    gemm_bt<0><<<dim3(32, 16), 256, 0, stream>>>(
        xb, DPAD, w1_pad, DPAD, DPAD / 64, hbuf, nullptr, N1, b11, b12);

    // fused stage-B + decode + symmetric-pair A2
    decode_f<<<BATCH / 16, 256, 0, stream>>>(hbuf, w2_pad, eps, b21, b22, W3, b3,
                                             W4, b4, W5, b5, fcyw, fcyb,
                                             out_mu, out_lv, out_y, A2);

    // GEMM2: recon = sigmoid(A2sym @ w6sym^T + b6)  M=4096 N=4736(valid 4624) K=2368
    gemm_bt<1><<<dim3(32, N2PAD / 128), 256, 0, stream>>>(
        A2, K2PAD, w6s, K2PAD, K2PAD / 64, nullptr, out_recon, DDIM, b6, nullptr);
}